// Round 10
// baseline (107.457 us; speedup 1.0000x reference)
//
#include <hip/hip_runtime.h>
#include <hip/hip_bf16.h>

#define N_NODES 50000
#define E_EDGES 1600000
#define IN_F    128
#define OUT_F   64
#define ALPHA   0.2f

#define BKT_SHIFT 8
#define BKT_NODES 256
#define NBKT 196                 // ceil(50000/256)
#define BKT_CAP 16384            // per-bucket record capacity (mean 8192, 90 sigma)
#define CHUNK 4096               // edges per binning block
#define NBLK_BIN 391             // ceil(1600000/4096)
#define NBLK_GEMM 782            // ceil(50000/64)
#define NBLK_AGG 12500           // per half

typedef __bf16 bf16x8 __attribute__((ext_vector_type(8)));
typedef float  f32x4  __attribute__((ext_vector_type(4)));

// round-to-nearest-even f32 -> bf16 bits
__device__ __forceinline__ unsigned f32_to_bf16_bits(float f) {
    unsigned u = __float_as_uint(f);
    return (u + 0x7FFFu + ((u >> 16) & 1u)) >> 16;
}

__device__ __forceinline__ float bf_lo(unsigned u) { return __uint_as_float(u << 16); }
__device__ __forceinline__ float bf_hi(unsigned u) { return __uint_as_float(u & 0xffff0000u); }

// ---------------------------------------------------------------------------
// K1 fused: blocks [0, NBLK_GEMM) run the MFMA GEMM (h = X@W + scores);
// blocks [NBLK_GEMM, ...) run the LDS counting-sort binning.
// h is stored feature-SPLIT: hbA = cols 0-31, hbB = cols 32-63 (3.2MB each,
// so each half fits a 4MB per-XCD L2 during the aggregate phases).
// ---------------------------------------------------------------------------
__global__ void __launch_bounds__(256)
gat_gemm_bin(const float* __restrict__ x, const float* __restrict__ W,
             const float* __restrict__ a,
             __hip_bfloat16* __restrict__ hbA, __hip_bfloat16* __restrict__ hbB,
             float* __restrict__ s_src, float* __restrict__ s_dst,
             const int* __restrict__ esrc, const int* __restrict__ edst,
             int* __restrict__ bcur, unsigned* __restrict__ recs_tmp) {
    if (blockIdx.x < NBLK_GEMM) {
        // ---- GEMM: one wave per 16 rows x 64 cols.
        // C/D layout: col = lane&15, row = (lane>>4)*4 + reg   [m89-verified]
        int wave = threadIdx.x >> 6;
        int lane = threadIdx.x & 63;
        int r0 = blockIdx.x * 64 + wave * 16;
        if (r0 >= N_NODES) return;                // 50000 = 781*64 + 16

        int col = lane & 15;
        int klo = (lane >> 4) * 8;

        bf16x8 bw[4][4];
#pragma unroll
        for (int t = 0; t < 4; ++t)
#pragma unroll
            for (int s = 0; s < 4; ++s)
#pragma unroll
                for (int j = 0; j < 8; ++j)
                    bw[t][s][j] = (__bf16)W[(32 * s + klo + j) * OUT_F + 16 * t + col];

        const float* xr = x + ((size_t)(r0 + col)) * IN_F;
        bf16x8 aw[4];
#pragma unroll
        for (int s = 0; s < 4; ++s) {
            float4 v0 = *(const float4*)(xr + 32 * s + klo);
            float4 v1 = *(const float4*)(xr + 32 * s + klo + 4);
            aw[s][0] = (__bf16)v0.x; aw[s][1] = (__bf16)v0.y;
            aw[s][2] = (__bf16)v0.z; aw[s][3] = (__bf16)v0.w;
            aw[s][4] = (__bf16)v1.x; aw[s][5] = (__bf16)v1.y;
            aw[s][6] = (__bf16)v1.z; aw[s][7] = (__bf16)v1.w;
        }

        f32x4 acc0 = {0.f,0.f,0.f,0.f}, acc1 = {0.f,0.f,0.f,0.f};
        f32x4 acc2 = {0.f,0.f,0.f,0.f}, acc3 = {0.f,0.f,0.f,0.f};
#pragma unroll
        for (int s = 0; s < 4; ++s) {
            acc0 = __builtin_amdgcn_mfma_f32_16x16x32_bf16(aw[s], bw[0][s], acc0, 0, 0, 0);
            acc1 = __builtin_amdgcn_mfma_f32_16x16x32_bf16(aw[s], bw[1][s], acc1, 0, 0, 0);
            acc2 = __builtin_amdgcn_mfma_f32_16x16x32_bf16(aw[s], bw[2][s], acc2, 0, 0, 0);
            acc3 = __builtin_amdgcn_mfma_f32_16x16x32_bf16(aw[s], bw[3][s], acc3, 0, 0, 0);
        }

        int grp = lane >> 4;
#pragma unroll
        for (int reg = 0; reg < 4; ++reg) {
            size_t baseh = (size_t)(r0 + grp * 4 + reg) * 32 + col;
            hbA[baseh +  0] = __float2bfloat16(acc0[reg]);   // cols 0-15
            hbA[baseh + 16] = __float2bfloat16(acc1[reg]);   // cols 16-31
            hbB[baseh +  0] = __float2bfloat16(acc2[reg]);   // cols 32-47
            hbB[baseh + 16] = __float2bfloat16(acc3[reg]);   // cols 48-63
        }

        float as0 = a[col], as1 = a[16 + col], as2 = a[32 + col], as3 = a[48 + col];
        float ad0 = a[64 + col], ad1 = a[80 + col], ad2 = a[96 + col], ad3 = a[112 + col];
#pragma unroll
        for (int reg = 0; reg < 4; ++reg) {
            float ps = acc0[reg] * as0 + acc1[reg] * as1 + acc2[reg] * as2 + acc3[reg] * as3;
            float pd = acc0[reg] * ad0 + acc1[reg] * ad1 + acc2[reg] * ad2 + acc3[reg] * ad3;
#pragma unroll
            for (int off = 1; off < 16; off <<= 1) {
                ps += __shfl_xor(ps, off, 64);
                pd += __shfl_xor(pd, off, 64);
            }
            if (col == 0) {
                s_src[r0 + grp * 4 + reg] = ps;
                s_dst[r0 + grp * 4 + reg] = pd;
            }
        }
    } else {
        // ---- BIN: LDS counting-sort of CHUNK edges by bucket (src>>8).
        __shared__ unsigned recs_l[CHUNK];     // 16KB
        __shared__ int cnt[NBKT];
        __shared__ int start[256];
        __shared__ int gbase[NBKT];
        __shared__ int sc[256];

        int t = threadIdx.x;
        int ebase = (blockIdx.x - NBLK_GEMM) * CHUNK;

        if (t < NBKT) cnt[t] = 0;
        __syncthreads();

        unsigned rec[16];
        int      loc[16];
#pragma unroll
        for (int k = 0; k < 16; ++k) {
            int e = ebase + k * 256 + t;
            if (e < E_EDGES) {
                unsigned s = (unsigned)esrc[e];
                unsigned d = (unsigned)edst[e];
                rec[k] = (s << 16) | d;
                loc[k] = atomicAdd(&cnt[s >> BKT_SHIFT], 1);
            } else {
                loc[k] = -1;
                rec[k] = 0;
            }
        }
        __syncthreads();

        int v = (t < NBKT) ? cnt[t] : 0;
        sc[t] = v;
        __syncthreads();
        for (int d = 1; d < 256; d <<= 1) {
            int add = (t >= d) ? sc[t - d] : 0;
            __syncthreads();
            sc[t] += add;
            __syncthreads();
        }
        start[t] = sc[t] - v;
        __syncthreads();

#pragma unroll
        for (int k = 0; k < 16; ++k)
            if (loc[k] >= 0)
                recs_l[start[rec[k] >> 24] + loc[k]] = rec[k];

        if (t < NBKT) {
            int c = cnt[t];
            gbase[t] = (c > 0) ? atomicAdd(&bcur[t], c) : 0;
        }
        __syncthreads();

        int total = min(CHUNK, E_EDGES - ebase);
        for (int i = t; i < total; i += 256) {
            unsigned r = recs_l[i];
            int b = r >> 24;
            int pos = gbase[b] + (i - start[b]);
            if (pos < (b + 1) * BKT_CAP)           // 90-sigma guard, never trips
                recs_tmp[pos] = r;
        }
    }
}

// ---------------------------------------------------------------------------
// K0: seed bucket cursors at fixed-stride region bases
// ---------------------------------------------------------------------------
__global__ void __launch_bounds__(256)
gat_init_cursors(int* __restrict__ bcur) {
    int t = threadIdx.x;
    if (t < NBKT) bcur[t] = t * BKT_CAP;
}

// ---------------------------------------------------------------------------
// K3: per-bucket pass, 1024 threads: LDS histogram -> rowptr/dcnt, then
// compute ee and place 4B records {dst:16 | ee:bf16} sorted-by-src.
// ---------------------------------------------------------------------------
__global__ void __launch_bounds__(1024)
gat_pass2(const int* __restrict__ bcur, const unsigned* __restrict__ recs_tmp,
          const float* __restrict__ s_src, const float* __restrict__ s_dst,
          int* __restrict__ rowptr, int* __restrict__ dcnt,
          unsigned* __restrict__ recs) {
    __shared__ int ncnt[256];
    __shared__ int lcur[256];
    __shared__ int sc[256];

    int b = blockIdx.x;
    int t = threadIdx.x;
    int nbase = b << BKT_SHIFT;
    int rbase = b * BKT_CAP;
    int m = bcur[b] - rbase;                       // records in this bucket

    if (t < 256) ncnt[t] = 0;
    __syncthreads();

    for (int i = t; i < m; i += 1024) {
        unsigned r = recs_tmp[rbase + i];
        atomicAdd(&ncnt[(r >> 16) & (BKT_NODES - 1)], 1);
    }
    __syncthreads();

    int v = 0;
    if (t < 256) { v = ncnt[t]; sc[t] = v; }
    __syncthreads();
    for (int d = 1; d < 256; d <<= 1) {
        int add = 0;
        if (t < 256 && t >= d) add = sc[t - d];
        __syncthreads();
        if (t < 256) sc[t] += add;
        __syncthreads();
    }
    if (t < 256) {
        int nstart = sc[t] - v;
        lcur[t] = nstart;
        int node = nbase + t;
        if (node < N_NODES) {
            rowptr[node] = rbase + nstart;
            dcnt[node]   = v;
        }
    }
    __syncthreads();

    for (int i = t; i < m; i += 1024) {
        unsigned r = recs_tmp[rbase + i];
        int s = r >> 16;
        int d = r & 0xFFFF;
        float sco = s_src[s] + s_dst[d];
        float lr = sco > 0.f ? sco : ALPHA * sco;
        float ee = __expf(-lr);
        int idx = atomicAdd(&lcur[s & (BKT_NODES - 1)], 1);
        recs[rbase + idx] = ((unsigned)d << 16) | f32_to_bf16_bits(ee);
    }
}

// ---------------------------------------------------------------------------
// K4: per-node segment reduction over a FEATURE-SPLIT h (two phases in one
// launch: blocks [0,NBLK_AGG) -> half A, [NBLK_AGG,2*NBLK_AGG) -> half B).
// Each half's gather array is 3.2MB -> L2-resident on every XCD.
// R7-proven wave structure: 256-thread blocks, quarter-wave per edge
// (16 lanes x 4B = full 64B row), register-staged records, unroll 8
// -> 8 independent gathers in flight per wave.
// ---------------------------------------------------------------------------
__global__ void __launch_bounds__(256)
gat_aggregate(const int* __restrict__ rowptr, const int* __restrict__ dcnt,
              const unsigned* __restrict__ recs,
              const __hip_bfloat16* __restrict__ hbA,
              const __hip_bfloat16* __restrict__ hbB,
              float* __restrict__ out) {
    int half = (blockIdx.x >= NBLK_AGG);
    int blk  = blockIdx.x - (half ? NBLK_AGG : 0);
    int node = blk * 4 + (threadIdx.x >> 6);
    int lane = threadIdx.x & 63;
    int q = lane >> 4;               // quarter 0..3
    int c = lane & 15;               // feature pair: features 2c, 2c+1 of half
    int beg = rowptr[node];
    int n   = dcnt[node];
    const unsigned* hbu = (const unsigned*)(half ? hbB : hbA);  // row = dst*16 + c

    float a0 = 0.f, a1 = 0.f, rs = 0.f;

    for (int base = 0; base < n; base += 64) {
        int m = n - base; if (m > 64) m = 64;
        unsigned rec = 0;
        if (lane < m) rec = recs[beg + base + lane];  // coalesced stage
        int nq = (m + 3) >> 2;                        // edges per quarter
#pragma unroll 8
        for (int k = 0; k < nq; ++k) {
            int j = q * nq + k;                       // this quarter's edge
            unsigned r = (unsigned)__shfl((int)rec, j, 64);
            float ee = (j < m) ? __uint_as_float((r & 0xFFFFu) << 16) : 0.f;
            unsigned u = hbu[(r >> 16) * 16 + c];
            a0 += ee * bf_lo(u);
            a1 += ee * bf_hi(u);
            rs += ee;
        }
    }

    // merge quarters (lanes sharing c): xor 16 then 32
    a0 += __shfl_xor(a0, 16, 64); a0 += __shfl_xor(a0, 32, 64);
    a1 += __shfl_xor(a1, 16, 64); a1 += __shfl_xor(a1, 32, 64);
    rs += __shfl_xor(rs, 16, 64); rs += __shfl_xor(rs, 32, 64);

    if (q == 0) {
        float inv = (rs != 0.f) ? 1.f / rs : 0.f;
        float v0 = a0 * inv, v1 = a1 * inv;
        v0 = v0 > 0.f ? v0 : (__expf(v0) - 1.f);
        v1 = v1 > 0.f ? v1 : (__expf(v1) - 1.f);
        *(float2*)(out + (size_t)node * OUT_F + half * 32 + 2 * c) =
            make_float2(v0, v1);
    }
}

// ---------------------------------------------------------------------------
extern "C" void kernel_launch(void* const* d_in, const int* in_sizes, int n_in,
                              void* d_out, int out_size, void* d_ws, size_t ws_size,
                              hipStream_t stream) {
    const float* x    = (const float*)d_in[0];
    const int*   edge = (const int*)d_in[1];   // (2, E) int32 row-major
    const float* W    = (const float*)d_in[2];
    const float* a    = (const float*)d_in[3];
    float*       out  = (float*)d_out;

    const int* esrc = edge;
    const int* edst = edge + E_EDGES;

    char* ws = (char*)d_ws;
    size_t off = 0;
    __hip_bfloat16* hbA = (__hip_bfloat16*)(ws + off); off += (size_t)N_NODES * 32 * 2; // 3.2MB
    __hip_bfloat16* hbB = (__hip_bfloat16*)(ws + off); off += (size_t)N_NODES * 32 * 2; // 3.2MB
    float* s_src  = (float*)(ws + off); off += (size_t)N_NODES * 4;
    float* s_dst  = (float*)(ws + off); off += (size_t)N_NODES * 4;
    int*   rowptr = (int*)  (ws + off); off += (size_t)N_NODES * 4;
    int*   dcnt   = (int*)  (ws + off); off += (size_t)N_NODES * 4;
    int*   bcur   = (int*)  (ws + off); off += 256 * 4;
    unsigned* recs_tmp = (unsigned*)(ws + off); off += (size_t)NBKT * BKT_CAP * 4;  // 12.8MB
    unsigned* recs     = (unsigned*)(ws + off); off += (size_t)NBKT * BKT_CAP * 4;  // 12.8MB

    gat_init_cursors<<<1, 256, 0, stream>>>(bcur);

    gat_gemm_bin<<<NBLK_GEMM + NBLK_BIN, 256, 0, stream>>>(
        x, W, a, hbA, hbB, s_src, s_dst, esrc, edst, bcur, recs_tmp);

    gat_pass2<<<NBKT, 1024, 0, stream>>>(bcur, recs_tmp, s_src, s_dst,
                                         rowptr, dcnt, recs);

    gat_aggregate<<<2 * NBLK_AGG, 256, 0, stream>>>(rowptr, dcnt, recs,
                                                    hbA, hbB, out);
}